// Round 6
// baseline (412.676 us; speedup 1.0000x reference)
//
#include <hip/hip_runtime.h>
#include <hip/hip_bf16.h>
#include <math.h>

// LSTM cell fused kernel, MI355X gfx950.
// B=65536, I=128, H=256, O=256, K=I+H=384.
// out = [log_softmax(combined@w_i2o.T+b_i2o) (B*256), new_hidden (B*256)]
//
// v7: 12 waves/CU via BM=32 + (256,3) under the unified residency model.
//  Model (fits v0-v6): resident waves/CU = min(4*arg2, LDS blocks, VGPR);
//  usable LDS ~128KiB; allocator splits unified file ~half arch/half accum
//  when arg2-constrained (arch cap = 2048/(waves)/2; VGPR_Count reports arch).
//  v6 was pinned at 8 waves by arg2=2 AND LDS=50176 (2 blocks).
//  - BM=32: LDS 32*392*2 = 25088 -> >=5 blocks LDS-wise; grid 2048.
//  - (256,3): 12-wave cap, arch budget 85. K-loop arch live ~65:
//    bfr[2][4]=32 + a[2]=8 + 4 B-ptrs + misc; acc[2][4]=32 lives in AGPR half.
//    (v5 spilled because its live set was ~150 under the same 85 cap.)
//  - softmax red buffers alias dead A-tile (phase-4 epilogue only).
//  Cost: weight L2 traffic doubles (2048 blocks x 983KB ~ 2GB -> ~59us
//  per-XCD-L2 floor) - below target, overlapped.

typedef __attribute__((ext_vector_type(8))) short bf16x8;   // 8 bf16 = 4 VGPRs
typedef __attribute__((ext_vector_type(4))) float f32x4;

#define BM   32     // rows per block
#define LDA  392    // padded LDS row stride in bf16 elems (384+8)
#define NW1  393216 // 1024*384
#define NW2  98304  // 256*384

__device__ __forceinline__ unsigned short f2bf(float f) {
    union { __hip_bfloat16 h; unsigned short u; } cv;
    cv.h = __float2bfloat16(f);
    return cv.u;
}
__device__ __forceinline__ float bf2f(unsigned short u) {
    union { __hip_bfloat16 h; unsigned short u; } cv;
    cv.u = u;
    return __bfloat162float(cv.h);
}
__device__ __forceinline__ float frcp(float x) {            // v_rcp_f32
    return __builtin_amdgcn_rcpf(x);
}
__device__ __forceinline__ float fsigmoid(float x) {
    return frcp(1.0f + __expf(-x));
}
__device__ __forceinline__ float ftanh(float x) {
    // tanh(x) = 1 - 2/(exp(2x)+1); robust at +-inf overflow of __expf
    return 1.0f - 2.0f * frcp(__expf(2.0f * x) + 1.0f);
}

// Convert fp32 weights -> bf16 into workspace. Runs every launch (ws is re-poisoned).
__global__ void conv_w(const float* __restrict__ w1, const float* __restrict__ w2,
                       unsigned short* __restrict__ wb) {
    int idx = blockIdx.x * 256 + threadIdx.x;   // per-float4; total (NW1+NW2)/4 = 122880
    const int n1 = NW1 / 4;
    float4 v;
    if (idx < n1) v = ((const float4*)w1)[idx];
    else          v = ((const float4*)w2)[idx - n1];
    ushort4 u;
    u.x = f2bf(v.x); u.y = f2bf(v.y); u.z = f2bf(v.z); u.w = f2bf(v.w);
    ((ushort4*)wb)[idx] = u;
}

__launch_bounds__(256, 3)
__global__ void lstm_fused(const float* __restrict__ input,    // [B,128]
                           const float* __restrict__ hidden,   // [B,256]
                           const unsigned short* __restrict__ w1b, // bf16 [1024][384]
                           const unsigned short* __restrict__ w2b, // bf16 [256][384]
                           const float* __restrict__ b1,       // [1024]
                           const float* __restrict__ b2,       // [256]
                           float* __restrict__ out_ls,         // [B,256]
                           float* __restrict__ out_nh)         // [B,256]
{
    // 25088 B. First 1024 B double as red_m/red_s in the phase-4 epilogue
    // (A is dead there; guarded by __syncthreads).
    __shared__ unsigned short A[BM * LDA];

    const int tid  = threadIdx.x;
    const int wave = tid >> 6;
    const int lane = tid & 63;
    const int l15  = lane & 15;
    const int quad = lane >> 4;
    const size_t r0 = (size_t)blockIdx.x * BM;

    // ---- phase-0 B pointers + slot-0 prime, issued BEFORE staging ----
    const unsigned short* bp[4];
    #pragma unroll
    for (int q = 0; q < 4; ++q)
        bp[q] = w1b + (size_t)(q * 256 + wave * 16 + l15) * 384 + quad * 8;
    bf16x8 bfr[2][4];
    #pragma unroll
    for (int nt = 0; nt < 4; ++nt) bfr[0][nt] = *(const bf16x8*)(bp[nt]);

    // ---- stage combined [32 x 384] fp32 -> bf16 LDS ----
    {
        const int row = tid >> 3;            // 0..31 (8 threads per row)
        const int c0  = tid & 7;
        const float4* si = (const float4*)(input  + (r0 + row) * 128);  // 32 float4
        const float4* sh = (const float4*)(hidden + (r0 + row) * 256);  // 64 float4
        ushort4* dst = (ushort4*)&A[row * LDA];
        #pragma unroll
        for (int i = 0; i < 12; ++i) {
            int c4 = c0 + 8 * i;             // 0..95; i<4 -> input cols, else hidden
            float4 v = (i < 4) ? si[c4] : sh[c4 - 32];
            union { __hip_bfloat162 h2; unsigned int u; } p0, p1;
            p0.h2 = __float22bfloat162_rn(make_float2(v.x, v.y));
            p1.h2 = __float22bfloat162_rn(make_float2(v.z, v.w));
            union { ushort4 s4; uint2 u2; } st;
            st.u2 = make_uint2(p0.u, p1.u);
            dst[c4] = st.s4;
        }
    }
    __syncthreads();

    // A-operand per-lane base: A[m = l15][k = quad*8 + j]
    const unsigned short* ap0 = &A[l15 * LDA + quad * 8];

    // 5 column phases: 0..3 = gate quadrant-interleaved, 4 = logits.
    #pragma unroll 1
    for (int phase = 0; phase < 5; ++phase) {
        f32x4 acc[2][4];
        #pragma unroll
        for (int i = 0; i < 2; ++i)
            #pragma unroll
            for (int jj = 0; jj < 4; ++jj)
                acc[i][jj] = (f32x4){0.f, 0.f, 0.f, 0.f};

        // K-loop: consume bfr[kk&1], fill bfr[(kk+1)&1] one step ahead.
        #pragma unroll
        for (int kk = 0; kk < 12; ++kk) {
            if (kk < 11) {
                #pragma unroll
                for (int nt = 0; nt < 4; ++nt)
                    bfr[(kk + 1) & 1][nt] = *(const bf16x8*)(bp[nt] + (kk + 1) * 32);
            }
            bf16x8 a[2];
            #pragma unroll
            for (int mt = 0; mt < 2; ++mt)
                a[mt] = *(const bf16x8*)(ap0 + mt * 16 * LDA + kk * 32);
            #pragma unroll
            for (int mt = 0; mt < 2; ++mt)
                #pragma unroll
                for (int nt = 0; nt < 4; ++nt)
                    acc[mt][nt] = __builtin_amdgcn_mfma_f32_16x16x32_bf16(
                        a[mt], bfr[kk & 1][nt], acc[mt][nt], 0, 0, 0);
        }

        // Next-phase pointers + slot-0 prime (slot 0 free: last consume was
        // bfr[1] at kk=11). Latency hides under this phase's epilogue VALU.
        if (phase < 4) {
            if (phase < 3) {
                int j0 = (phase + 1) * 64 + wave * 16 + l15;
                #pragma unroll
                for (int q = 0; q < 4; ++q)
                    bp[q] = w1b + (size_t)(q * 256 + j0) * 384 + quad * 8;
            } else {
                #pragma unroll
                for (int nt = 0; nt < 4; ++nt)
                    bp[nt] = w2b + (size_t)(wave * 64 + nt * 16 + l15) * 384 + quad * 8;
            }
            #pragma unroll
            for (int nt = 0; nt < 4; ++nt)
                bfr[0][nt] = *(const bf16x8*)(bp[nt]);
        }

        const int j = phase * 64 + wave * 16 + l15;   // output col within group

        if (phase < 4) {
            // acc[mt][q][r] = gates[row = mt*16+quad*4+r][q*256 + j]
            float bq0 = b1[j], bq1 = b1[256 + j], bq2 = b1[512 + j], bq3 = b1[768 + j];
            #pragma unroll
            for (int mt = 0; mt < 2; ++mt) {
                #pragma unroll
                for (int r = 0; r < 4; ++r) {
                    int rowl = mt * 16 + quad * 4 + r;
                    float hprev = bf2f(A[rowl * LDA + 128 + j]);
                    float hv  = ftanh(acc[mt][0][r] + bq0);
                    float igv = fsigmoid(acc[mt][1][r] + bq1);
                    float fgv = fsigmoid(acc[mt][2][r] + bq2);
                    float ogv = fsigmoid(acc[mt][3][r] + bq3);
                    out_nh[(r0 + rowl) * 256 + j] = ogv * ftanh(fgv * hprev + igv * hv);
                }
            }
        } else {
            // acc[mt][nt][r] = logits[row][col = wave*64 + nt*16 + l15]
            float bo[4];
            #pragma unroll
            for (int nt = 0; nt < 4; ++nt) bo[nt] = b2[wave * 64 + nt * 16 + l15];
            #pragma unroll
            for (int mt = 0; mt < 2; ++mt)
                #pragma unroll
                for (int nt = 0; nt < 4; ++nt)
                    #pragma unroll
                    for (int r = 0; r < 4; ++r)
                        acc[mt][nt][r] += bo[nt];

            // per-row max: reduce over nt in-lane, then over l15 via xor-butterfly
            float pm[2][4], ps[2][4];
            #pragma unroll
            for (int mt = 0; mt < 2; ++mt)
                #pragma unroll
                for (int r = 0; r < 4; ++r) {
                    float m = acc[mt][0][r];
                    #pragma unroll
                    for (int nt = 1; nt < 4; ++nt) m = fmaxf(m, acc[mt][nt][r]);
                    pm[mt][r] = m;
                }
            #pragma unroll
            for (int mask = 1; mask < 16; mask <<= 1)
                #pragma unroll
                for (int mt = 0; mt < 2; ++mt)
                    #pragma unroll
                    for (int r = 0; r < 4; ++r)
                        pm[mt][r] = fmaxf(pm[mt][r], __shfl_xor(pm[mt][r], mask, 64));
            #pragma unroll
            for (int mt = 0; mt < 2; ++mt)
                #pragma unroll
                for (int r = 0; r < 4; ++r) {
                    float s = 0.f;
                    #pragma unroll
                    for (int nt = 0; nt < 4; ++nt)
                        s += __expf(acc[mt][nt][r] - pm[mt][r]);
                    ps[mt][r] = s;
                }
            #pragma unroll
            for (int mask = 1; mask < 16; mask <<= 1)
                #pragma unroll
                for (int mt = 0; mt < 2; ++mt)
                    #pragma unroll
                    for (int r = 0; r < 4; ++r)
                        ps[mt][r] += __shfl_xor(ps[mt][r], mask, 64);

            // A is dead from here on; alias its first 1024 B as red buffers.
            __syncthreads();                    // all waves done reading A
            float* red = (float*)A;             // red_m = red[0..127], red_s = red[128..255]
            if (l15 == 0) {
                #pragma unroll
                for (int mt = 0; mt < 2; ++mt)
                    #pragma unroll
                    for (int r = 0; r < 4; ++r) {
                        int rowl = mt * 16 + quad * 4 + r;
                        red[wave * 32 + rowl]       = pm[mt][r];
                        red[128 + wave * 32 + rowl] = ps[mt][r];
                    }
            }
            __syncthreads();
            #pragma unroll
            for (int mt = 0; mt < 2; ++mt)
                #pragma unroll
                for (int r = 0; r < 4; ++r) {
                    int rowl = mt * 16 + quad * 4 + r;
                    float M = red[rowl];
                    #pragma unroll
                    for (int w = 1; w < 4; ++w) M = fmaxf(M, red[w * 32 + rowl]);
                    float S = 0.f;
                    #pragma unroll
                    for (int w = 0; w < 4; ++w)
                        S += red[128 + w * 32 + rowl] * __expf(red[w * 32 + rowl] - M);
                    float lz = M + 0.69314718055994531f * __log2f(S);
                    #pragma unroll
                    for (int nt = 0; nt < 4; ++nt)
                        out_ls[(r0 + rowl) * 256 + wave * 64 + nt * 16 + l15] =
                            acc[mt][nt][r] - lz;
                }
        }
    }
}

extern "C" void kernel_launch(void* const* d_in, const int* in_sizes, int n_in,
                              void* d_out, int out_size, void* d_ws, size_t ws_size,
                              hipStream_t stream) {
    const float* input  = (const float*)d_in[0];
    const float* hidden = (const float*)d_in[1];
    const float* w1     = (const float*)d_in[2];
    const float* b1     = (const float*)d_in[3];
    const float* w2     = (const float*)d_in[4];
    const float* b2     = (const float*)d_in[5];
    float* out = (float*)d_out;
    unsigned short* wb = (unsigned short*)d_ws;   // needs 983040 B

    conv_w<<<dim3((NW1 + NW2) / 4 / 256), dim3(256), 0, stream>>>(w1, w2, wb);
    lstm_fused<<<dim3(65536 / BM), dim3(256), 0, stream>>>(
        input, hidden, wb, wb + NW1, b1, b2,
        out, out + (size_t)65536 * 256);
}